// Round 1
// 512.625 us; speedup vs baseline: 1.0642x; 1.0642x over previous
//
#include <hip/hip_runtime.h>
#include <math.h>

#define BB 64
#define HH 1024
#define II 128
#define AA 16
#define ECOLS 819           // int(0.8*1024)
#define ALPHA_X 0.2f        // dt/tau_x
#define ALPHA_W 0.02f       // dt/tau_w
#define DTC 0.02f
#define CHUNK 16            // batches per chunk: 16*4MB = 64 MB wh slab in LLC

typedef float v4f __attribute__((ext_vector_type(4)));

// -------- Phase 1: recurrent drive + leaky integration + retanh ----------
// grid = CHUNK * (H/16) blocks, 1024 threads (16 waves); wave w handles
// row i = itile*16 + w of batch b = b0 + (blockIdx>>6).
__global__ __launch_bounds__(1024) void phase1(
    const float* __restrict__ x, const float* __restrict__ state,
    const float* __restrict__ output, const float* __restrict__ wh,
    const float* __restrict__ da, const float* __restrict__ aux_x,
    const float* __restrict__ Wx, const float* __restrict__ Waux,
    const float* __restrict__ bh,
    float* __restrict__ new_state, float* __restrict__ new_output,
    float* __restrict__ crow, int b0)
{
    __shared__ float so[HH];     // signed output row for batch b
    __shared__ float xr[II];     // relu(x[b,:])
    __shared__ float auxr[AA];   // relu(aux_x[b,:])

    const int tid   = threadIdx.x;
    const int b     = b0 + (blockIdx.x >> 6);  // 64 row-tiles per batch
    const int itile = blockIdx.x & 63;

    {
        float o = output[b * HH + tid];
        so[tid] = (tid < ECOLS) ? o : -o;
    }
    if (tid < II)  xr[tid]   = fmaxf(x[b * II + tid], 0.0f);
    if (tid < AA)  auxr[tid] = fmaxf(aux_x[b * AA + tid], 0.0f);
    __syncthreads();

    const int lane = tid & 63;
    const int w    = tid >> 6;
    const int i    = itile * 16 + w;

    const float* whrow = wh + ((size_t)b * HH + i) * HH;

    float acc = 0.0f;
    #pragma unroll
    for (int c = 0; c < 4; ++c) {
        int j = c * 256 + lane * 4;
        v4f a = *reinterpret_cast<const v4f*>(whrow + j);   // default-cached:
        v4f s = *reinterpret_cast<const v4f*>(so + j);      // we WANT LLC allocate
        acc += a.x * s.x + a.y * s.y + a.z * s.z + a.w * s.w;
    }
    // feedforward: |W_x| (128 cols over 2 iters) and |W_aux| (16 cols)
    const float* wxr = Wx + (size_t)i * II;
    acc += xr[lane]      * fabsf(wxr[lane]);
    acc += xr[lane + 64] * fabsf(wxr[lane + 64]);
    if (lane < AA) acc += auxr[lane] * fabsf(Waux[(size_t)i * AA + lane]);

    // wave reduction (64 lanes)
    #pragma unroll
    for (int off = 32; off > 0; off >>= 1)
        acc += __shfl_xor(acc, off);

    if (lane == 0) {
        float total = acc - whrow[i] * so[i] + bh[i];
        float ns = state[b * HH + i] * (1.0f - ALPHA_X) + total * ALPHA_X;
        float no = tanhf(fmaxf(ns, 0.0f));   // retanh
        new_state[b * HH + i]  = ns;
        new_output[b * HH + i] = no;
        crow[b * HH + i]       = DTC * da[b] * no;
    }
}

// -------- Phase 2: additive Hebbian plasticity + clip (per batch chunk) ----
// Streams the chunk's wh slab (hot in LLC from phase1) and writes nw with
// non-temporal stores so the write stream doesn't evict the slab.
__global__ __launch_bounds__(256) void phase2(
    const float* __restrict__ wh, const float* __restrict__ Whh,
    const float* __restrict__ kappa, const float* __restrict__ no,
    const float* __restrict__ crow, float* __restrict__ nw, int b0)
{
    const int    N4    = CHUNK * HH * (HH / 4);       // float4s in this chunk
    const size_t base4 = (size_t)b0 * HH * (HH / 4);
    const int stride = gridDim.x * blockDim.x;
    int idx = blockIdx.x * blockDim.x + threadIdx.x;

    for (; idx < N4; idx += stride) {
        const int j4   = idx & 255;          // H/4 float4s per row
        const int lrow = idx >> 8;           // (b-b0)*H + i
        const int i    = lrow & (HH - 1);
        const int b    = b0 + (lrow >> 10);
        const size_t g4 = base4 + idx;

        // last use of this wh line: non-temporal (still hits LLC if resident)
        v4f wv = __builtin_nontemporal_load(reinterpret_cast<const v4f*>(wh) + g4);
        v4f wa = reinterpret_cast<const v4f*>(Whh)  [(i << 8) + j4];
        v4f ka = reinterpret_cast<const v4f*>(kappa)[(i << 8) + j4];
        v4f nj = reinterpret_cast<const v4f*>(no)   [((size_t)b << 8) + j4];
        const float c = crow[(size_t)b * HH + i];

        v4f r;
        r.x = fminf(fmaxf(ALPHA_W * fabsf(wa.x) + (1.0f - ALPHA_W) * wv.x + c * fabsf(ka.x) * nj.x, 0.0f), 1.0f);
        r.y = fminf(fmaxf(ALPHA_W * fabsf(wa.y) + (1.0f - ALPHA_W) * wv.y + c * fabsf(ka.y) * nj.y, 0.0f), 1.0f);
        r.z = fminf(fmaxf(ALPHA_W * fabsf(wa.z) + (1.0f - ALPHA_W) * wv.z + c * fabsf(ka.z) * nj.z, 0.0f), 1.0f);
        r.w = fminf(fmaxf(ALPHA_W * fabsf(wa.w) + (1.0f - ALPHA_W) * wv.w + c * fabsf(ka.w) * nj.w, 0.0f), 1.0f);

        // streaming write: don't pollute LLC (keep wh slab resident)
        __builtin_nontemporal_store(r, reinterpret_cast<v4f*>(nw) + g4);
    }
}

extern "C" void kernel_launch(void* const* d_in, const int* in_sizes, int n_in,
                              void* d_out, int out_size, void* d_ws, size_t ws_size,
                              hipStream_t stream) {
    const float* x      = (const float*)d_in[0];
    const float* state  = (const float*)d_in[1];
    const float* output = (const float*)d_in[2];
    const float* wh     = (const float*)d_in[3];
    const float* da     = (const float*)d_in[4];
    const float* aux_x  = (const float*)d_in[5];
    const float* Wx     = (const float*)d_in[6];
    const float* Waux   = (const float*)d_in[7];
    const float* Whh    = (const float*)d_in[8];
    const float* bh     = (const float*)d_in[9];
    const float* kappa  = (const float*)d_in[10];
    // d_in[11] = mask_h: recomputed analytically (sign + zero diagonal)

    float* out        = (float*)d_out;
    float* new_state  = out;
    float* new_output = out + (size_t)BB * HH;
    float* new_w      = out + (size_t)2 * BB * HH;
    float* crow       = (float*)d_ws;        // B*H floats = 256 KB scratch

    // Chunk batches so phase2 re-reads phase1's wh slab out of the 256 MB
    // Infinity Cache instead of HBM (64 MB slab + 64 MB nw stream << 256 MB).
    for (int b0 = 0; b0 < BB; b0 += CHUNK) {
        phase1<<<dim3(CHUNK * (HH / 16)), dim3(1024), 0, stream>>>(
            x, state, output, wh, da, aux_x, Wx, Waux, bh,
            new_state, new_output, crow, b0);

        phase2<<<dim3(2048), dim3(256), 0, stream>>>(
            wh, Whh, kappa, new_output, crow, new_w, b0);
    }
}